// Round 1
// baseline (4002.280 us; speedup 1.0000x reference)
//
#include <hip/hip_runtime.h>
#include <math.h>

// WaveNet backbone, fp32 baseline.
// Layout decisions:
//  - outputs region of d_out doubles as the h chain: layer i reads h from
//    outputs[i], writes h_next to outputs[i+1] (last layer -> d_ws).
//  - Per-layer fused kernel: one block = 32 time steps x all 128 channels.
//    5 matmuls (dil0, dil1, tanh, sig, skip) + gating fused; x_dil and x_h
//    round-trip through LDS so every thread sees all 128 input channels.

namespace {
constexpr int C  = 128;   // residual channels
constexpr int S_ = 128;   // skip channels
constexpr int T  = 8192;
constexpr int B_ = 2;
constexpr int L_ = 20;
constexpr int TT = 32;    // time tile per block
constexpr int DIL[L_] = {1,2,4,8,16,32,64,128,256,512,
                         1,2,4,8,16,32,64,128,256,512};
}

__global__ __launch_bounds__(256) void in_conv(
    const float* __restrict__ x, const float* __restrict__ w_in,
    const float* __restrict__ b_in, float* __restrict__ h0)
{
    int idx = blockIdx.x * 256 + threadIdx.x;   // over B*C*T = 2^21
    int t = idx & (T - 1);
    int c = (idx >> 13) & (C - 1);              // T = 2^13
    int b = idx >> 20;                          // C*T = 2^20
    h0[idx] = w_in[c] * x[b * T + t] + b_in[c];
}

// block 256 threads: thread = (t: tid&31, c_group: tid>>5), 16 c_out each.
__global__ __launch_bounds__(256, 2) void layer_k(
    const float* __restrict__ h_in,  // [B,C,T]
    float* __restrict__ h_out,       // [B,C,T]
    float* __restrict__ skip_out,    // [B,S,T]
    const float* __restrict__ wd, const float* __restrict__ bd,
    const float* __restrict__ wt, const float* __restrict__ bt,
    const float* __restrict__ wsg, const float* __restrict__ bs,
    const float* __restrict__ wk, const float* __restrict__ bk,
    int d)
{
    __shared__ float h_cur[C][TT];
    __shared__ float h_prv[C][TT];   // reused as x_h buffer in phase 3
    __shared__ float xd[C][TT];

    const int tile = blockIdx.x;
    const int b    = blockIdx.y;
    const int t0   = tile * TT;
    const float* hb = h_in + (size_t)b * C * T;
    const int tid = threadIdx.x;

    // ---- stage h tiles into LDS ----
    for (int f = tid; f < C * TT / 4; f += 256) {       // vectorized current tile
        int c  = f >> 3;                                // TT/4 = 8
        int tq = f & 7;
        *(float4*)&h_cur[c][tq * 4] = *(const float4*)&hb[c * T + t0 + tq * 4];
    }
    for (int f = tid; f < C * TT; f += 256) {           // guarded dilated tile
        int c  = f >> 5;
        int tt = f & 31;
        int ts = t0 + tt - d;
        h_prv[c][tt] = (ts >= 0) ? hb[c * T + ts] : 0.0f;
    }
    __syncthreads();

    const int t  = tid & 31;
    const int c0 = (tid >> 5) * 16;

    // ---- phase 1: x_dil = W0 @ h[t-d] + W1 @ h[t] + b_dil ----
    float acc[16];
#pragma unroll
    for (int j = 0; j < 16; ++j) acc[j] = bd[c0 + j];
    for (int ci = 0; ci < C; ci += 4) {
        float hp[4], hc[4];
#pragma unroll
        for (int q = 0; q < 4; ++q) { hp[q] = h_prv[ci + q][t]; hc[q] = h_cur[ci + q][t]; }
#pragma unroll
        for (int j = 0; j < 16; ++j) {
            // w_dil layout [C_out][C_in][2]: float4 = {w0[ci],w1[ci],w0[ci+1],w1[ci+1]}
            const float4 wa = *(const float4*)&wd[((c0 + j) * C + ci) * 2];
            const float4 wb = *(const float4*)&wd[((c0 + j) * C + ci + 2) * 2];
            acc[j] += wa.x * hp[0] + wa.y * hc[0] + wa.z * hp[1] + wa.w * hc[1]
                    + wb.x * hp[2] + wb.y * hc[2] + wb.z * hp[3] + wb.w * hc[3];
        }
    }
#pragma unroll
    for (int j = 0; j < 16; ++j) xd[c0 + j][t] = acc[j];
    __syncthreads();

    // ---- phase 2: gated activation + residual write ----
    float at[16], as[16];
#pragma unroll
    for (int j = 0; j < 16; ++j) { at[j] = bt[c0 + j]; as[j] = bs[c0 + j]; }
    for (int ci = 0; ci < C; ci += 4) {
        float xv[4];
#pragma unroll
        for (int q = 0; q < 4; ++q) xv[q] = xd[ci + q][t];
#pragma unroll
        for (int j = 0; j < 16; ++j) {
            const float4 w1 = *(const float4*)&wt [(c0 + j) * C + ci];
            const float4 w2 = *(const float4*)&wsg[(c0 + j) * C + ci];
            at[j] += w1.x * xv[0] + w1.y * xv[1] + w1.z * xv[2] + w1.w * xv[3];
            as[j] += w2.x * xv[0] + w2.y * xv[1] + w2.z * xv[2] + w2.w * xv[3];
        }
    }
    float* ho = h_out + (size_t)b * C * T;
    float xh[16];
#pragma unroll
    for (int j = 0; j < 16; ++j) {
        float tv = 1.0f - 2.0f / (__expf(2.0f * at[j]) + 1.0f);   // tanh
        float sv = 1.0f / (1.0f + __expf(-as[j]));                // sigmoid
        xh[j] = tv * sv;
        ho[(c0 + j) * T + t0 + t] = xh[j] + acc[j];               // h_next = x_h + x_dil
    }
    // h_prv is only read in phase 1 (barrier above guarantees done) -> reuse for x_h
#pragma unroll
    for (int j = 0; j < 16; ++j) h_prv[c0 + j][t] = xh[j];
    __syncthreads();

    // ---- phase 3: skip = W_skip @ x_h + b_skip ----
    float ak[16];
#pragma unroll
    for (int j = 0; j < 16; ++j) ak[j] = bk[c0 + j];
    for (int ci = 0; ci < C; ci += 4) {
        float xv[4];
#pragma unroll
        for (int q = 0; q < 4; ++q) xv[q] = h_prv[ci + q][t];
#pragma unroll
        for (int j = 0; j < 16; ++j) {
            const float4 w1 = *(const float4*)&wk[(c0 + j) * C + ci];
            ak[j] += w1.x * xv[0] + w1.y * xv[1] + w1.z * xv[2] + w1.w * xv[3];
        }
    }
    float* so = skip_out + (size_t)b * S_ * T;
#pragma unroll
    for (int j = 0; j < 16; ++j) so[(c0 + j) * T + t0 + t] = ak[j];
}

extern "C" void kernel_launch(void* const* d_in, const int* in_sizes, int n_in,
                              void* d_out, int out_size, void* d_ws, size_t ws_size,
                              hipStream_t stream)
{
    const float* x      = (const float*)d_in[0];
    const float* w_in   = (const float*)d_in[1];
    const float* b_in   = (const float*)d_in[2];
    const float* w_dil  = (const float*)d_in[3];
    const float* b_dil  = (const float*)d_in[4];
    const float* w_tanh = (const float*)d_in[5];
    const float* b_tanh = (const float*)d_in[6];
    const float* w_sig  = (const float*)d_in[7];
    const float* b_sig  = (const float*)d_in[8];
    const float* w_skip = (const float*)d_in[9];
    const float* b_skip = (const float*)d_in[10];

    float* outs  = (float*)d_out;                        // [L,B,C,T]
    float* skips = outs + (size_t)L_ * B_ * C * T;       // [L,B,S,T]
    float* hlast = (float*)d_ws;                         // discarded final h

    in_conv<<<dim3(B_ * C * T / 256), dim3(256), 0, stream>>>(x, w_in, b_in, outs);

    for (int i = 0; i < L_; ++i) {
        const float* h_in  = outs + (size_t)i * B_ * C * T;
        float* h_out = (i + 1 < L_) ? outs + (size_t)(i + 1) * B_ * C * T : hlast;
        float* sk_o  = skips + (size_t)i * B_ * S_ * T;
        layer_k<<<dim3(T / TT, B_), dim3(256), 0, stream>>>(
            h_in, h_out, sk_o,
            w_dil  + (size_t)i * C * C * 2, b_dil  + (size_t)i * C,
            w_tanh + (size_t)i * C * C,     b_tanh + (size_t)i * C,
            w_sig  + (size_t)i * C * C,     b_sig  + (size_t)i * C,
            w_skip + (size_t)i * S_ * C,    b_skip + (size_t)i * C,
            DIL[i]);
    }
}

// Round 2
// 755.520 us; speedup vs baseline: 5.2974x; 5.2974x over previous
//
#include <hip/hip_runtime.h>
#include <math.h>

// WaveNet backbone, fp16-MFMA version.
//  - h chain lives in d_out (outputs[i] is layer i's input); last h -> d_ws.
//  - Per-layer fused kernel: block = 4 waves = 128 c_out x 64 t.
//    Phase 1: x_dil = [W0|W1] @ [h_prv;h_cur]  (K=256 MFMA), fp32 acc kept in regs.
//    Phase 2: tanh/sig convs (K=128) on x_dil (fp16 via LDS), gated epilogue,
//             h_next = x_h + x_dil written fp32.
//    Phase 3: skip conv (K=128) on x_h.
//  - MFMA 16x16x32 f16 layouts (m89/m91/m120-verified):
//      A[m=lane&15][k=(lane>>4)*8+j], B[k=(lane>>4)*8+j][n=lane&15],
//      D[row=(lane>>4)*4+r][col=lane&15].
//  - LDS: sh = B^T tile [t][k=0..255] pitch 264 fp16 (pad 8 -> 2-way banks, free);
//         sx = x_dil fp16 [t][c] pitch 136; sxh aliases sh after phase 1.

typedef _Float16 half8 __attribute__((ext_vector_type(8)));
typedef float floatx4 __attribute__((ext_vector_type(4)));

namespace {
constexpr int C  = 128;
constexpr int S_ = 128;
constexpr int T  = 8192;
constexpr int B_ = 2;
constexpr int L_ = 20;
constexpr int NT = 64;        // time tile per block
constexpr int P1 = 264;       // 256 + 8 fp16 pad (528B rows, 16B aligned)
constexpr int P2 = 136;       // 128 + 8 fp16 pad (272B rows, 16B aligned)
constexpr int DIL[L_] = {1,2,4,8,16,32,64,128,256,512,
                         1,2,4,8,16,32,64,128,256,512};
}

__device__ __forceinline__ float fast_tanh(float x) { return 1.0f - 2.0f / (__expf(2.0f * x) + 1.0f); }
__device__ __forceinline__ float fast_sig (float x) { return 1.0f / (1.0f + __expf(-x)); }

__global__ __launch_bounds__(256) void in_conv(
    const float* __restrict__ x, const float* __restrict__ w_in,
    const float* __restrict__ b_in, float* __restrict__ h0)
{
    int idx = blockIdx.x * 256 + threadIdx.x;   // over B*C*T = 2^21
    int t = idx & (T - 1);
    int c = (idx >> 13) & (C - 1);
    int b = idx >> 20;
    h0[idx] = w_in[c] * x[b * T + t] + b_in[c];
}

__global__ __launch_bounds__(256, 1) void layer_k(
    const float* __restrict__ h_in,  // [B,C,T]
    float* __restrict__ h_out,       // [B,C,T]
    float* __restrict__ skip_out,    // [B,S,T]
    const float* __restrict__ wd, const float* __restrict__ bd,
    const float* __restrict__ wt, const float* __restrict__ bt,
    const float* __restrict__ wsg, const float* __restrict__ bs,
    const float* __restrict__ wk, const float* __restrict__ bk,
    int d)
{
    __shared__ _Float16 sh[NT * P1];   // [t][k]: k<128 = h[t-d][ci], k>=128 = h[t][ci]
    __shared__ _Float16 sx[NT * P2];   // x_dil fp16, [t][c]
    _Float16* sxh = sh;                // x_h fp16, [t][c] — reuses sh after phase 1

    const int tid = threadIdx.x;
    const int b   = blockIdx.y;
    const int t0  = blockIdx.x * NT;
    const float* hb = h_in + (size_t)b * C * T;

    // ---- stage h tiles (global [c][t] -> LDS [t][k], fp16) ----
    for (int f = tid; f < C * (NT / 4); f += 256) {      // current tap -> cols 128+ci
        int ci = f >> 4, tq = f & 15;
        float4 v = *(const float4*)&hb[ci * T + t0 + tq * 4];
        _Float16* p = &sh[(tq * 4) * P1 + 128 + ci];
        p[0] = (_Float16)v.x; p[P1] = (_Float16)v.y;
        p[2 * P1] = (_Float16)v.z; p[3 * P1] = (_Float16)v.w;
    }
    if ((d & 3) == 0) {                                   // dilated tap, aligned float4
        for (int f = tid; f < C * (NT / 4); f += 256) {
            int ci = f >> 4, tq = f & 15;
            int ts = t0 + tq * 4 - d;
            float4 v = make_float4(0.f, 0.f, 0.f, 0.f);
            if (ts >= 0) v = *(const float4*)&hb[ci * T + ts];
            _Float16* p = &sh[(tq * 4) * P1 + ci];
            p[0] = (_Float16)v.x; p[P1] = (_Float16)v.y;
            p[2 * P1] = (_Float16)v.z; p[3 * P1] = (_Float16)v.w;
        }
    } else {                                              // d in {1,2}: scalar guarded
        for (int f = tid; f < C * NT; f += 256) {
            int ci = f >> 6, tt = f & 63;
            int ts = t0 + tt - d;
            sh[tt * P1 + ci] = (ts >= 0) ? (_Float16)hb[ci * T + ts] : (_Float16)0.0f;
        }
    }
    __syncthreads();

    const int lane = tid & 63;
    const int wv   = tid >> 6;      // 0..3
    const int m16  = lane & 15;     // m (A row) / n (B col) / D col
    const int q    = lane >> 4;     // 0..3
    const int cb   = wv * 32;       // wave's c_out base: 2 m-tiles

    // ===== phase 1: x_dil, K=256 =====
    half8 wdf[2][8];
#pragma unroll
    for (int mt = 0; mt < 2; ++mt) {
        const float4* wr = (const float4*)(wd + (size_t)(cb + mt * 16 + m16) * 256);
#pragma unroll
        for (int hf = 0; hf < 4; ++hf) {
            // 16 consecutive floats = w_dil[row][hf*32+q*8 .. +8][0..1] interleaved
            float4 f0 = wr[hf * 16 + q * 4 + 0];
            float4 f1 = wr[hf * 16 + q * 4 + 1];
            float4 f2 = wr[hf * 16 + q * 4 + 2];
            float4 f3 = wr[hf * 16 + q * 4 + 3];
            wdf[mt][hf] = (half8){(_Float16)f0.x, (_Float16)f0.z, (_Float16)f1.x, (_Float16)f1.z,
                                  (_Float16)f2.x, (_Float16)f2.z, (_Float16)f3.x, (_Float16)f3.z};
            wdf[mt][hf + 4] = (half8){(_Float16)f0.y, (_Float16)f0.w, (_Float16)f1.y, (_Float16)f1.w,
                                      (_Float16)f2.y, (_Float16)f2.w, (_Float16)f3.y, (_Float16)f3.w};
        }
    }
    floatx4 bias_d[2];
#pragma unroll
    for (int mt = 0; mt < 2; ++mt)
#pragma unroll
        for (int r = 0; r < 4; ++r) bias_d[mt][r] = bd[cb + mt * 16 + q * 4 + r];

    floatx4 xdacc[2][4];
#pragma unroll
    for (int nt = 0; nt < 4; ++nt) {
        const _Float16* br = &sh[(nt * 16 + m16) * P1 + q * 8];
        half8 bf[8];
#pragma unroll
        for (int kc = 0; kc < 8; ++kc) bf[kc] = *(const half8*)(br + kc * 32);
#pragma unroll
        for (int mt = 0; mt < 2; ++mt) {
            floatx4 acc = bias_d[mt];
#pragma unroll
            for (int kc = 0; kc < 8; ++kc)
                acc = __builtin_amdgcn_mfma_f32_16x16x32_f16(wdf[mt][kc], bf[kc], acc, 0, 0, 0);
            xdacc[mt][nt] = acc;
            _Float16* px = &sx[(nt * 16 + m16) * P2 + cb + mt * 16 + q * 4];
#pragma unroll
            for (int r = 0; r < 4; ++r) px[r] = (_Float16)acc[r];
        }
    }
    __syncthreads();   // sx ready; sh free for reuse as sxh

    // ===== phase 2: tanh/sig convs + gate + residual, K=128 =====
    half8 wtf[2][4], wsf[2][4];
#pragma unroll
    for (int mt = 0; mt < 2; ++mt) {
        const int row = cb + mt * 16 + m16;
#pragma unroll
        for (int kc = 0; kc < 4; ++kc) {
            const float4* p1 = (const float4*)(wt + (size_t)row * 128 + kc * 32 + q * 8);
            float4 a0 = p1[0], a1 = p1[1];
            wtf[mt][kc] = (half8){(_Float16)a0.x, (_Float16)a0.y, (_Float16)a0.z, (_Float16)a0.w,
                                  (_Float16)a1.x, (_Float16)a1.y, (_Float16)a1.z, (_Float16)a1.w};
            const float4* p2 = (const float4*)(wsg + (size_t)row * 128 + kc * 32 + q * 8);
            float4 b0 = p2[0], b1 = p2[1];
            wsf[mt][kc] = (half8){(_Float16)b0.x, (_Float16)b0.y, (_Float16)b0.z, (_Float16)b0.w,
                                  (_Float16)b1.x, (_Float16)b1.y, (_Float16)b1.z, (_Float16)b1.w};
        }
    }
    floatx4 bias_t[2], bias_s[2];
#pragma unroll
    for (int mt = 0; mt < 2; ++mt)
#pragma unroll
        for (int r = 0; r < 4; ++r) {
            bias_t[mt][r] = bt[cb + mt * 16 + q * 4 + r];
            bias_s[mt][r] = bs[cb + mt * 16 + q * 4 + r];
        }

    float* ho = h_out + (size_t)b * C * T;
#pragma unroll
    for (int nt = 0; nt < 4; ++nt) {
        const _Float16* br = &sx[(nt * 16 + m16) * P2 + q * 8];
        half8 bf[4];
#pragma unroll
        for (int kc = 0; kc < 4; ++kc) bf[kc] = *(const half8*)(br + kc * 32);
#pragma unroll
        for (int mt = 0; mt < 2; ++mt) {
            floatx4 at = bias_t[mt], as = bias_s[mt];
#pragma unroll
            for (int kc = 0; kc < 4; ++kc) {
                at = __builtin_amdgcn_mfma_f32_16x16x32_f16(wtf[mt][kc], bf[kc], at, 0, 0, 0);
                as = __builtin_amdgcn_mfma_f32_16x16x32_f16(wsf[mt][kc], bf[kc], as, 0, 0, 0);
            }
            _Float16* pxh = &sxh[(nt * 16 + m16) * P2 + cb + mt * 16 + q * 4];
#pragma unroll
            for (int r = 0; r < 4; ++r) {
                float xh = fast_tanh(at[r]) * fast_sig(as[r]);
                pxh[r] = (_Float16)xh;
                ho[(size_t)(cb + mt * 16 + q * 4 + r) * T + t0 + nt * 16 + m16]
                    = xh + xdacc[mt][nt][r];
            }
        }
    }
    __syncthreads();   // sxh ready

    // ===== phase 3: skip conv, K=128 =====
    half8 wkf[2][4];
#pragma unroll
    for (int mt = 0; mt < 2; ++mt) {
        const int row = cb + mt * 16 + m16;
#pragma unroll
        for (int kc = 0; kc < 4; ++kc) {
            const float4* p1 = (const float4*)(wk + (size_t)row * 128 + kc * 32 + q * 8);
            float4 a0 = p1[0], a1 = p1[1];
            wkf[mt][kc] = (half8){(_Float16)a0.x, (_Float16)a0.y, (_Float16)a0.z, (_Float16)a0.w,
                                  (_Float16)a1.x, (_Float16)a1.y, (_Float16)a1.z, (_Float16)a1.w};
        }
    }
    floatx4 bias_k[2];
#pragma unroll
    for (int mt = 0; mt < 2; ++mt)
#pragma unroll
        for (int r = 0; r < 4; ++r) bias_k[mt][r] = bk[cb + mt * 16 + q * 4 + r];

    float* so = skip_out + (size_t)b * S_ * T;
#pragma unroll
    for (int nt = 0; nt < 4; ++nt) {
        const _Float16* br = &sxh[(nt * 16 + m16) * P2 + q * 8];
        half8 bf[4];
#pragma unroll
        for (int kc = 0; kc < 4; ++kc) bf[kc] = *(const half8*)(br + kc * 32);
#pragma unroll
        for (int mt = 0; mt < 2; ++mt) {
            floatx4 ak = bias_k[mt];
#pragma unroll
            for (int kc = 0; kc < 4; ++kc)
                ak = __builtin_amdgcn_mfma_f32_16x16x32_f16(wkf[mt][kc], bf[kc], ak, 0, 0, 0);
#pragma unroll
            for (int r = 0; r < 4; ++r)
                so[(size_t)(cb + mt * 16 + q * 4 + r) * T + t0 + nt * 16 + m16] = ak[r];
        }
    }
}

extern "C" void kernel_launch(void* const* d_in, const int* in_sizes, int n_in,
                              void* d_out, int out_size, void* d_ws, size_t ws_size,
                              hipStream_t stream)
{
    const float* x      = (const float*)d_in[0];
    const float* w_in   = (const float*)d_in[1];
    const float* b_in   = (const float*)d_in[2];
    const float* w_dil  = (const float*)d_in[3];
    const float* b_dil  = (const float*)d_in[4];
    const float* w_tanh = (const float*)d_in[5];
    const float* b_tanh = (const float*)d_in[6];
    const float* w_sig  = (const float*)d_in[7];
    const float* b_sig  = (const float*)d_in[8];
    const float* w_skip = (const float*)d_in[9];
    const float* b_skip = (const float*)d_in[10];

    float* outs  = (float*)d_out;                        // [L,B,C,T]
    float* skips = outs + (size_t)L_ * B_ * C * T;       // [L,B,S,T]
    float* hlast = (float*)d_ws;                         // discarded final h

    in_conv<<<dim3(B_ * C * T / 256), dim3(256), 0, stream>>>(x, w_in, b_in, outs);

    for (int i = 0; i < L_; ++i) {
        const float* h_in  = outs + (size_t)i * B_ * C * T;
        float* h_out = (i + 1 < L_) ? outs + (size_t)(i + 1) * B_ * C * T : hlast;
        float* sk_o  = skips + (size_t)i * B_ * S_ * T;
        layer_k<<<dim3(T / NT, B_), dim3(256), 0, stream>>>(
            h_in, h_out, sk_o,
            w_dil  + (size_t)i * C * C * 2, b_dil  + (size_t)i * C,
            w_tanh + (size_t)i * C * C,     b_tanh + (size_t)i * C,
            w_sig  + (size_t)i * C * C,     b_sig  + (size_t)i * C,
            w_skip + (size_t)i * S_ * C,    b_skip + (size_t)i * C,
            DIL[i]);
    }
}